// Round 7
// baseline (212.085 us; speedup 1.0000x reference)
//
#include <hip/hip_runtime.h>
#include <math.h>

#define Bx 2
#define Sx 2048
#define Dx 1024
#define Hx 16
#define HDx 64
#define Mx (Bx*Sx)   // 4096

typedef __bf16 bf16x8 __attribute__((ext_vector_type(8)));
typedef __bf16 bf16x4 __attribute__((ext_vector_type(4)));
typedef float  f32x4  __attribute__((ext_vector_type(4)));

// 0.125 (1/sqrt(64)) * log2(e): softmax in exp2 domain; folded into Q in GEMM1
#define SCL 0.18033688011112042f

__device__ __forceinline__ void gload_lds16(const __bf16* g, __bf16* l) {
  __builtin_amdgcn_global_load_lds(
      (const __attribute__((address_space(1))) unsigned int*)g,
      (__attribute__((address_space(3))) unsigned int*)l, 16, 0, 0);
}

// ---------------- fp32 -> bf16 conversion / weight concat ----------------
__device__ __forceinline__ void cvt8(const float* s, __bf16* d) {
  float4 a = *(const float4*)s;
  float4 b = *(const float4*)(s + 4);
  bf16x8 o;
  o[0] = (__bf16)a.x; o[1] = (__bf16)a.y; o[2] = (__bf16)a.z; o[3] = (__bf16)a.w;
  o[4] = (__bf16)b.x; o[5] = (__bf16)b.y; o[6] = (__bf16)b.z; o[7] = (__bf16)b.w;
  *(bf16x8*)d = o;
}

__global__ __launch_bounds__(256) void cvt_kernel(
    const float* __restrict__ x, const float* __restrict__ Wq,
    const float* __restrict__ Wk, const float* __restrict__ Wv,
    const float* __restrict__ Wo, const float* __restrict__ bq,
    const float* __restrict__ bk, const float* __restrict__ bv,
    __bf16* __restrict__ xb, __bf16* __restrict__ wqkv,
    __bf16* __restrict__ wob, float* __restrict__ bqkv)
{
  const int bid = blockIdx.x;
  const int t = threadIdx.x;
  const size_t MEG = 1024u * 1024u;
  if (bid < 2048) {
    size_t e = (size_t)bid * 2048 + t * 8;
    cvt8(x + e, xb + e);
  } else if (bid < 3584) {
    size_t e = (size_t)(bid - 2048) * 2048 + t * 8;
    const float* src = (e < MEG) ? (Wq + e) : (e < 2 * MEG) ? (Wk + (e - MEG)) : (Wv + (e - 2 * MEG));
    cvt8(src, wqkv + e);
  } else if (bid < 4096) {
    size_t e = (size_t)(bid - 3584) * 2048 + t * 8;
    cvt8(Wo + e, wob + e);
  } else {
    for (int i = t; i < 3072; i += 256)
      bqkv[i] = (i < 1024) ? bq[i] : (i < 2048) ? bk[i - 1024] : bv[i - 2048];
  }
}

// ---------------- bf16 MFMA GEMM: C[M,N] = A[M,K] @ W[N,K]^T + bias ----------------
// BK=64, XOR-swizzled LDS image via swizzled *source* addressing of
// global_load_lds (dest stays lane-contiguous per the m104 constraint).
// MODE 0: fp32 row store. MODE 1: bf16 to qkv (Q pre-scaled by SCL), V->vT.
template<int TM, int TN, int MODE>
__global__ __launch_bounds__(256) void gemm_k(
    const __bf16* __restrict__ A, const __bf16* __restrict__ W,
    const float* __restrict__ bias, float* __restrict__ Cf,
    __bf16* __restrict__ Cb, __bf16* __restrict__ vT,
    int M, int N, int K, int ldc)
{
  constexpr int MS = TM / 32;
  constexpr int NS = TN / 32;
  __shared__ __bf16 As[TM * 64];
  __shared__ __bf16 Bs[TN * 64];
  const int tid = threadIdx.x;
  const int lane = tid & 63, wave = tid >> 6;
  const int l16 = lane & 15, quad = lane >> 4;
  const int wm = (wave >> 1) * (TM / 2);
  const int wn = (wave & 1) * (TN / 2);
  const int m0 = blockIdx.y * TM;
  const int n0 = blockIdx.x * TN;
  const int swz = l16 & 7;

  const f32x4 zero = {0.f, 0.f, 0.f, 0.f};
  f32x4 acc[MS][NS];
#pragma unroll
  for (int i = 0; i < MS; ++i)
#pragma unroll
    for (int j = 0; j < NS; ++j) acc[i][j] = zero;

  const int srow = tid >> 3;
  const int scs = (tid & 7) ^ (srow & 7);
  const __bf16* Ag = A + (size_t)(m0 + srow) * K + scs * 8;
  const __bf16* Wg = W + (size_t)(n0 + srow) * K + scs * 8;

  for (int k0 = 0; k0 < K; k0 += 64) {
    __syncthreads();
#pragma unroll
    for (int i = 0; i < TM / 32; ++i)
      gload_lds16(Ag + (size_t)(i * 32) * K + k0, &As[(i * 256 + tid) * 8]);
#pragma unroll
    for (int i = 0; i < TN / 32; ++i)
      gload_lds16(Wg + (size_t)(i * 32) * K + k0, &Bs[(i * 256 + tid) * 8]);
    __syncthreads();

#pragma unroll
    for (int hk = 0; hk < 2; ++hk) {
      const int ph = ((hk * 4 + quad) ^ swz) * 8;
      bf16x8 af[MS], bfr[NS];
#pragma unroll
      for (int i = 0; i < MS; ++i)
        af[i] = *(const bf16x8*)&As[(wm + i * 16 + l16) * 64 + ph];
#pragma unroll
      for (int j = 0; j < NS; ++j)
        bfr[j] = *(const bf16x8*)&Bs[(wn + j * 16 + l16) * 64 + ph];
#pragma unroll
      for (int i = 0; i < MS; ++i)
#pragma unroll
        for (int j = 0; j < NS; ++j)
          acc[i][j] = __builtin_amdgcn_mfma_f32_16x16x32_bf16(af[i], bfr[j], acc[i][j], 0, 0, 0);
    }
  }

  const int cbase = n0 + wn + l16;
#pragma unroll
  for (int j = 0; j < NS; ++j) {
    const int c = cbase + j * 16;
    const float bv_ = bias[c];
#pragma unroll
    for (int i = 0; i < MS; ++i) {
      const int r0 = m0 + wm + i * 16 + quad * 4;
      if (MODE == 0) {
#pragma unroll
        for (int g = 0; g < 4; ++g)
          Cf[(size_t)(r0 + g) * ldc + c] = acc[i][j][g] + bv_;
      } else {
        if (c < 2048) {
          const float sc = (c < 1024) ? SCL : 1.0f;
#pragma unroll
          for (int g = 0; g < 4; ++g)
            Cb[(size_t)(r0 + g) * 3072 + c] = (__bf16)((acc[i][j][g] + bv_) * sc);
        } else {
          const int c2 = c - 2048;
          const int hh = c2 >> 6, dd = c2 & 63;
          const int bb = r0 >> 11, ss = r0 & 2047;
          bf16x4 st;
          st[0] = (__bf16)(acc[i][j][0] + bv_);
          st[1] = (__bf16)(acc[i][j][1] + bv_);
          st[2] = (__bf16)(acc[i][j][2] + bv_);
          st[3] = (__bf16)(acc[i][j][3] + bv_);
          *(bf16x4*)&vT[((size_t)(bb * 16 + hh) * 64 + dd) * 2048 + ss] = st;
        }
      }
    }
  }
}

// ---------------- MFMA flash attention, 128-row Q-tile, 2 q-streams/wave ----
// No-max softmax (scores bounded; shift-invariance). Each wave owns 32 q-rows
// as TWO independent 16-row streams -> 2x ILP on every chain stage; K/V frag
// reads shared across streams. S pipelined one tile ahead; K staged at
// distance 2 (double-buffered; extra barrier after pre-loop S protects buf0),
// V at distance 1 (double-buffered). l via ones-column MFMA. P aliases the
// wave's own 32-row Q slice. One barrier per k-tile.
__global__ __launch_bounds__(256) void attn_mfma(
    const __bf16* __restrict__ qkv, const __bf16* __restrict__ vT,
    __bf16* __restrict__ zb)
{
  __shared__ __bf16 Qs[128 * 64];     // Q; later per-wave P slices (32 rows each)
  __shared__ __bf16 Ks[2][64 * 64];
  __shared__ __bf16 Vs[2][64 * 64];   // [d][k] (from vT)

  const int tid = threadIdx.x;
  const int lane = tid & 63, wave = tid >> 6;
  const int l16 = lane & 15, quad = lane >> 4;
  const int swz = l16 & 7;
  const int bx = blockIdx.x;
  const int qtg = bx >> 5;
  const int qt = (qtg < 8) ? (15 - qtg) : (qtg - 8);  // heavy/light pairing
  const int bh = bx & 31;
  const int h = bh & 15, b = bh >> 4;
  const int q0 = qt * 128;
  const int nk = 2 * qt + 2;

  const __bf16* qg = qkv + (size_t)b * 2048 * 3072 + h * 64;
  const __bf16* kg = qg + 1024;
  const __bf16* vg = vT + (size_t)bh * 64 * 2048;

#define STAGE_K(kt_, kb)                                                        \
  { const int kn = (kt_) * 64;                                                  \
    _Pragma("unroll")                                                           \
    for (int i = 0; i < 2; ++i) {                                               \
      int slot = i * 256 + tid;                                                 \
      int row = slot >> 3;                                                      \
      int cs = (slot & 7) ^ (row & 7);                                          \
      gload_lds16(kg + (size_t)(kn + row) * 3072 + cs * 8, &Ks[kb][slot * 8]);  \
    } }

#define STAGE_V(kt_, vb)                                                        \
  { const int kn = (kt_) * 64;                                                  \
    _Pragma("unroll")                                                           \
    for (int i = 0; i < 2; ++i) {                                               \
      int slot = i * 256 + tid;                                                 \
      int row = slot >> 3;                                                      \
      int cs = (slot & 7) ^ (row & 7);                                          \
      gload_lds16(vg + (size_t)row * 2048 + kn + cs * 8, &Vs[vb][slot * 8]);    \
    } }

  // prologue: Q (128 rows), K0, V0, K1
#pragma unroll
  for (int i = 0; i < 4; ++i) {
    int slot = i * 256 + tid;
    int row = slot >> 3;
    int cs = (slot & 7) ^ (row & 7);
    gload_lds16(qg + (size_t)(q0 + row) * 3072 + cs * 8, &Qs[slot * 8]);
  }
  STAGE_K(0, 0)
  STAGE_V(0, 0)
  STAGE_K(1, 1)
  __syncthreads();

  // Q fragments: 2 streams x 2 k-chunks (loop-invariant)
  bf16x8 qf[2][2];
#pragma unroll
  for (int s = 0; s < 2; ++s)
#pragma unroll
    for (int kk = 0; kk < 2; ++kk)
      qf[s][kk] = *(const bf16x8*)&Qs[(wave * 32 + s * 16 + l16) * 64 + ((kk * 4 + quad) ^ swz) * 8];
  __bf16* P = &Qs[wave * 32 * 64];    // this wave's own 32x64 slice

  bf16x8 onesf;
  {
    __bf16 ov = (l16 == 0) ? (__bf16)1.0f : (__bf16)0.0f;
#pragma unroll
    for (int i = 0; i < 8; ++i) onesf[i] = ov;
  }

  const f32x4 zero = {0.f, 0.f, 0.f, 0.f};
  f32x4 O[2][4], Ol[2];
#pragma unroll
  for (int s = 0; s < 2; ++s) {
    Ol[s] = zero;
#pragma unroll
    for (int j = 0; j < 4; ++j) O[s][j] = zero;
  }
  f32x4 s_cur[2][4], s_next[2][4];

#define S_TILE(sd, kb)                                                          \
  { _Pragma("unroll")                                                           \
    for (int s = 0; s < 2; ++s)                                                 \
      _Pragma("unroll")                                                         \
      for (int j = 0; j < 4; ++j) sd[s][j] = zero;                              \
    _Pragma("unroll")                                                           \
    for (int kk = 0; kk < 2; ++kk)                                              \
      _Pragma("unroll")                                                         \
      for (int j = 0; j < 4; ++j) {                                             \
        bf16x8 kf = *(const bf16x8*)&Ks[kb][(j * 16 + l16) * 64 + ((kk * 4 + quad) ^ swz) * 8]; \
        sd[0][j] = __builtin_amdgcn_mfma_f32_16x16x32_bf16(qf[0][kk], kf, sd[0][j], 0, 0, 0);  \
        sd[1][j] = __builtin_amdgcn_mfma_f32_16x16x32_bf16(qf[1][kk], kf, sd[1][j], 0, 0, 0);  \
      } }

#define EXP_P(sv, MASK, k0_)                                                    \
  { _Pragma("unroll")                                                           \
    for (int s = 0; s < 2; ++s)                                                 \
      _Pragma("unroll")                                                         \
      for (int j = 0; j < 4; ++j) {                                             \
        const int cg = (k0_) + j * 16 + l16;                                    \
        _Pragma("unroll")                                                       \
        for (int g = 0; g < 4; ++g) {                                           \
          float p = __builtin_exp2f(sv[s][j][g]);                               \
          if (MASK && cg > (q0 + wave * 32 + s * 16 + quad * 4 + g)) p = 0.f;   \
          sv[s][j][g] = p;                                                      \
        }                                                                       \
      }                                                                         \
    _Pragma("unroll")                                                           \
    for (int s = 0; s < 2; ++s)                                                 \
      _Pragma("unroll")                                                         \
      for (int j = 0; j < 4; ++j) {                                             \
        const int ch = j * 2 + (l16 >> 3);                                      \
        _Pragma("unroll")                                                       \
        for (int g = 0; g < 4; ++g) {                                           \
          const int rl = s * 16 + quad * 4 + g;                                 \
          P[rl * 64 + ((ch ^ (rl & 7)) * 8) + (l16 & 7)] = (__bf16)sv[s][j][g]; \
        }                                                                       \
      } }

#define PV_TILE(vb)                                                             \
  { _Pragma("unroll")                                                           \
    for (int kk = 0; kk < 2; ++kk) {                                            \
      bf16x8 pf0 = *(const bf16x8*)&P[(l16) * 64 + ((kk * 4 + quad) ^ swz) * 8];         \
      bf16x8 pf1 = *(const bf16x8*)&P[(16 + l16) * 64 + ((kk * 4 + quad) ^ swz) * 8];    \
      _Pragma("unroll")                                                         \
      for (int j = 0; j < 4; ++j) {                                             \
        bf16x8 vf = *(const bf16x8*)&Vs[vb][(j * 16 + l16) * 64 + ((kk * 4 + quad) ^ swz) * 8]; \
        O[0][j] = __builtin_amdgcn_mfma_f32_16x16x32_bf16(pf0, vf, O[0][j], 0, 0, 0);    \
        O[1][j] = __builtin_amdgcn_mfma_f32_16x16x32_bf16(pf1, vf, O[1][j], 0, 0, 0);    \
      }                                                                         \
      Ol[0] = __builtin_amdgcn_mfma_f32_16x16x32_bf16(pf0, onesf, Ol[0], 0, 0, 0);       \
      Ol[1] = __builtin_amdgcn_mfma_f32_16x16x32_bf16(pf1, onesf, Ol[1], 0, 0, 0);       \
    } }

#define SCOPY                                                                   \
  { _Pragma("unroll")                                                           \
    for (int s = 0; s < 2; ++s)                                                 \
      _Pragma("unroll")                                                         \
      for (int j = 0; j < 4; ++j) s_cur[s][j] = s_next[s][j]; }

  S_TILE(s_cur, 0)
  __syncthreads();   // all waves' S(0) reads drained before iter-0 restages Ks[0]

  for (int t = 0; t <= nk - 3; ++t) {
    STAGE_K(t + 2, t & 1)
    STAGE_V(t + 1, (t + 1) & 1)
    EXP_P(s_cur, false, t * 64)
    S_TILE(s_next, (t + 1) & 1)
    PV_TILE(t & 1)
    __syncthreads();
    SCOPY
  }
  // peel nk-2 (partially masked)
  STAGE_V(nk - 1, (nk - 1) & 1)
  EXP_P(s_cur, true, (nk - 2) * 64)
  S_TILE(s_next, (nk - 1) & 1)
  PV_TILE((nk - 2) & 1)
  __syncthreads();
  SCOPY
  // peel nk-1 (masked)
  EXP_P(s_cur, true, (nk - 1) * 64)
  PV_TILE((nk - 1) & 1)

  // epilogue: l in col 0 of Ol (lanes quad*16); O/l -> zb
#pragma unroll
  for (int s = 0; s < 2; ++s) {
#pragma unroll
    for (int g = 0; g < 4; ++g) {
      const float lv = __shfl(Ol[s][g], quad * 16);
      const float inv = 1.0f / lv;
      const int rq = q0 + wave * 32 + s * 16 + quad * 4 + g;
      const size_t rb = (size_t)(b * 2048 + rq) * 1024 + h * 64 + l16;
#pragma unroll
      for (int j = 0; j < 4; ++j)
        zb[rb + j * 16] = (__bf16)(O[s][j][g] * inv);
    }
  }
}

// ---------------- launch ----------------
extern "C" void kernel_launch(void* const* d_in, const int* in_sizes, int n_in,
                              void* d_out, int out_size, void* d_ws, size_t ws_size,
                              hipStream_t stream) {
  (void)in_sizes; (void)n_in; (void)out_size; (void)ws_size;
  const float* x  = (const float*)d_in[0];
  const float* Wq = (const float*)d_in[1];
  const float* bq = (const float*)d_in[2];
  const float* Wk = (const float*)d_in[3];
  const float* bk = (const float*)d_in[4];
  const float* Wv = (const float*)d_in[5];
  const float* bv = (const float*)d_in[6];
  const float* Wo = (const float*)d_in[7];
  const float* bo = (const float*)d_in[8];

  char* ws = (char*)d_ws;
  __bf16* xb   = (__bf16*)(ws);                        // 8 MB
  __bf16* wqkv = (__bf16*)(ws + (8ull  << 20));        // 6 MB
  __bf16* wob  = (__bf16*)(ws + (14ull << 20));        // 2 MB
  float*  bqkv = (float*) (ws + (16ull << 20));        // 12 KB
  __bf16* qkv  = (__bf16*)(ws + (17ull << 20));        // 24 MB
  __bf16* vT   = (__bf16*)(ws + (41ull << 20));        // 8 MB  [bh][64][2048]
  __bf16* zb   = (__bf16*)(ws + (49ull << 20));        // 8 MB  (total 57 MB)

  cvt_kernel<<<4097, 256, 0, stream>>>(x, Wq, Wk, Wv, Wo, bq, bk, bv,
                                       xb, wqkv, wob, bqkv);
  gemm_k<128, 128, 1><<<dim3(24, 32), 256, 0, stream>>>(
      xb, wqkv, bqkv, nullptr, qkv, vT, Mx, 3072, 1024, 0);
  attn_mfma<<<512, 256, 0, stream>>>(qkv, vT, zb);
  gemm_k<128, 64, 0><<<dim3(16, 32), 256, 0, stream>>>(
      zb, wob, bo, (float*)d_out, nullptr, nullptr, Mx, 1024, 1024, 1024);
}

// Round 8
// 194.272 us; speedup vs baseline: 1.0917x; 1.0917x over previous
//
#include <hip/hip_runtime.h>
#include <math.h>

#define Bx 2
#define Sx 2048
#define Dx 1024
#define Hx 16
#define HDx 64
#define Mx (Bx*Sx)   // 4096

typedef __bf16 bf16x8 __attribute__((ext_vector_type(8)));
typedef __bf16 bf16x4 __attribute__((ext_vector_type(4)));
typedef float  f32x4  __attribute__((ext_vector_type(4)));

// 0.125 (1/sqrt(64)) * log2(e): softmax in exp2 domain; folded into Q in GEMM1
#define SCL 0.18033688011112042f

__device__ __forceinline__ void gload_lds16(const __bf16* g, __bf16* l) {
  __builtin_amdgcn_global_load_lds(
      (const __attribute__((address_space(1))) unsigned int*)g,
      (__attribute__((address_space(3))) unsigned int*)l, 16, 0, 0);
}

// ---------------- fp32 -> bf16 conversion / weight concat ----------------
__device__ __forceinline__ void cvt8(const float* s, __bf16* d) {
  float4 a = *(const float4*)s;
  float4 b = *(const float4*)(s + 4);
  bf16x8 o;
  o[0] = (__bf16)a.x; o[1] = (__bf16)a.y; o[2] = (__bf16)a.z; o[3] = (__bf16)a.w;
  o[4] = (__bf16)b.x; o[5] = (__bf16)b.y; o[6] = (__bf16)b.z; o[7] = (__bf16)b.w;
  *(bf16x8*)d = o;
}

__global__ __launch_bounds__(256) void cvt_kernel(
    const float* __restrict__ x, const float* __restrict__ Wq,
    const float* __restrict__ Wk, const float* __restrict__ Wv,
    const float* __restrict__ Wo, const float* __restrict__ bq,
    const float* __restrict__ bk, const float* __restrict__ bv,
    __bf16* __restrict__ xb, __bf16* __restrict__ wqkv,
    __bf16* __restrict__ wob, float* __restrict__ bqkv)
{
  const int bid = blockIdx.x;
  const int t = threadIdx.x;
  const size_t MEG = 1024u * 1024u;
  if (bid < 2048) {
    size_t e = (size_t)bid * 2048 + t * 8;
    cvt8(x + e, xb + e);
  } else if (bid < 3584) {
    size_t e = (size_t)(bid - 2048) * 2048 + t * 8;
    const float* src = (e < MEG) ? (Wq + e) : (e < 2 * MEG) ? (Wk + (e - MEG)) : (Wv + (e - 2 * MEG));
    cvt8(src, wqkv + e);
  } else if (bid < 4096) {
    size_t e = (size_t)(bid - 3584) * 2048 + t * 8;
    cvt8(Wo + e, wob + e);
  } else {
    for (int i = t; i < 3072; i += 256)
      bqkv[i] = (i < 1024) ? bq[i] : (i < 2048) ? bk[i - 1024] : bv[i - 2048];
  }
}

// ---------------- bf16 MFMA GEMM: C[M,N] = A[M,K] @ W[N,K]^T + bias ----------------
// BK=64, XOR-swizzled LDS image via swizzled *source* addressing of
// global_load_lds. Epilogue round-trips the C tile through LDS (aliasing
// As/Bs) so ALL global stores are 16B with 16 consecutive lanes = 256B runs.
// MODE 0: fp32 out (ldc). MODE 1: bf16 qkv (Q pre-scaled by SCL) for
// n0<2048; V tiles (n0>=2048) staged TRANSPOSED in LDS -> coalesced vT.
template<int TM, int TN, int MODE>
__global__ __launch_bounds__(256) void gemm_k(
    const __bf16* __restrict__ A, const __bf16* __restrict__ W,
    const float* __restrict__ bias, float* __restrict__ Cf,
    __bf16* __restrict__ Cb, __bf16* __restrict__ vT,
    int M, int N, int K, int ldc)
{
  __shared__ __align__(16) char smem[35840];
  __bf16* As = (__bf16*)smem;
  __bf16* Bs = (__bf16*)(smem + (size_t)TM * 64 * 2);

  constexpr int MS = TM / 32;
  constexpr int NS = TN / 32;
  const int tid = threadIdx.x;
  const int lane = tid & 63, wave = tid >> 6;
  const int l16 = lane & 15, quad = lane >> 4;
  const int wm = (wave >> 1) * (TM / 2);
  const int wn = (wave & 1) * (TN / 2);
  const int m0 = blockIdx.y * TM;
  const int n0 = blockIdx.x * TN;
  const int swz = l16 & 7;

  const f32x4 zero = {0.f, 0.f, 0.f, 0.f};
  f32x4 acc[MS][NS];
#pragma unroll
  for (int i = 0; i < MS; ++i)
#pragma unroll
    for (int j = 0; j < NS; ++j) acc[i][j] = zero;

  const int srow = tid >> 3;
  const int scs = (tid & 7) ^ (srow & 7);
  const __bf16* Ag = A + (size_t)(m0 + srow) * K + scs * 8;
  const __bf16* Wg = W + (size_t)(n0 + srow) * K + scs * 8;

  for (int k0 = 0; k0 < K; k0 += 64) {
    __syncthreads();
#pragma unroll
    for (int i = 0; i < TM / 32; ++i)
      gload_lds16(Ag + (size_t)(i * 32) * K + k0, &As[(i * 256 + tid) * 8]);
#pragma unroll
    for (int i = 0; i < TN / 32; ++i)
      gload_lds16(Wg + (size_t)(i * 32) * K + k0, &Bs[(i * 256 + tid) * 8]);
    __syncthreads();

#pragma unroll
    for (int hk = 0; hk < 2; ++hk) {
      const int ph = ((hk * 4 + quad) ^ swz) * 8;
      bf16x8 af[MS], bfr[NS];
#pragma unroll
      for (int i = 0; i < MS; ++i)
        af[i] = *(const bf16x8*)&As[(wm + i * 16 + l16) * 64 + ph];
#pragma unroll
      for (int j = 0; j < NS; ++j)
        bfr[j] = *(const bf16x8*)&Bs[(wn + j * 16 + l16) * 64 + ph];
#pragma unroll
      for (int i = 0; i < MS; ++i)
#pragma unroll
        for (int j = 0; j < NS; ++j)
          acc[i][j] = __builtin_amdgcn_mfma_f32_16x16x32_bf16(af[i], bfr[j], acc[i][j], 0, 0, 0);
    }
  }

  // ---- epilogue: stage C tile in LDS (aliases As/Bs), vector stores ----
  __syncthreads();   // all waves done reading As/Bs
  if (MODE == 0) {
    float* Cs = (float*)smem;          // [TM][TN+4]
    constexpr int cst = TN + 4;
#pragma unroll
    for (int j = 0; j < NS; ++j) {
      const int c = wn + j * 16 + l16;
      const float bv_ = bias[n0 + c];
#pragma unroll
      for (int i = 0; i < MS; ++i) {
        const int r0 = wm + i * 16 + quad * 4;
#pragma unroll
        for (int g = 0; g < 4; ++g)
          Cs[(r0 + g) * cst + c] = acc[i][j][g] + bv_;
      }
    }
    __syncthreads();
    constexpr int passes = TM * TN / (256 * 4);
#pragma unroll
    for (int p = 0; p < passes; ++p) {
      const int slot = p * 256 + tid;
      const int row = slot / (TN / 4);
      const int col4 = (slot % (TN / 4)) * 4;
      f32x4 v = *(const f32x4*)&Cs[row * cst + col4];
      *(f32x4*)&Cf[(size_t)(m0 + row) * ldc + n0 + col4] = v;
    }
  } else {
    __bf16* Cs = (__bf16*)smem;        // [TM][136] or transposed [TN][136]
    constexpr int cst = TN + 8;
    const bool vtile = (n0 >= 2048);
    if (!vtile) {
#pragma unroll
      for (int j = 0; j < NS; ++j) {
        const int c = wn + j * 16 + l16;
        const float bv_ = bias[n0 + c];
        const float sc = ((n0 + c) < 1024) ? SCL : 1.0f;
#pragma unroll
        for (int i = 0; i < MS; ++i) {
          const int r0 = wm + i * 16 + quad * 4;
#pragma unroll
          for (int g = 0; g < 4; ++g)
            Cs[(r0 + g) * cst + c] = (__bf16)((acc[i][j][g] + bv_) * sc);
        }
      }
      __syncthreads();
      constexpr int passes = TM * TN / (256 * 8);
#pragma unroll
      for (int p = 0; p < passes; ++p) {
        const int slot = p * 256 + tid;
        const int row = slot / (TN / 8);
        const int col8 = (slot % (TN / 8)) * 8;
        bf16x8 v = *(const bf16x8*)&Cs[row * cst + col8];
        *(bf16x8*)&Cb[(size_t)(m0 + row) * 3072 + n0 + col8] = v;
      }
    } else {
      // transposed staging: Cs[c_local][m_local]
      constexpr int cstT = TM + 8;
#pragma unroll
      for (int j = 0; j < NS; ++j) {
        const int c = wn + j * 16 + l16;
        const float bv_ = bias[n0 + c];
#pragma unroll
        for (int i = 0; i < MS; ++i) {
          const int r0 = wm + i * 16 + quad * 4;
#pragma unroll
          for (int g = 0; g < 4; ++g)
            Cs[c * cstT + r0 + g] = (__bf16)(acc[i][j][g] + bv_);
        }
      }
      __syncthreads();
      const int bb = m0 >> 11, ml = m0 & 2047;
      constexpr int passes = TM * TN / (256 * 8);
#pragma unroll
      for (int p = 0; p < passes; ++p) {
        const int slot = p * 256 + tid;
        const int dd = slot / (TM / 8);           // tile-local col (c)
        const int ss8 = (slot % (TM / 8)) * 8;    // tile-local row (m)
        bf16x8 v = *(const bf16x8*)&Cs[dd * cstT + ss8];
        const int c2 = n0 - 2048 + dd;
        const int hh = c2 >> 6, ddd = c2 & 63;
        *(bf16x8*)&vT[((size_t)(bb * 16 + hh) * 64 + ddd) * 2048 + ml + ss8] = v;
      }
    }
  }
}

// ---------------- MFMA flash attention (round-6 version, 48.4 us) ----------
// No-max softmax (scores bounded; shift-invariance). S pipelined one tile
// ahead; K double-buffered (distance 2), V triple-buffered. l via ones-column
// MFMA. P aliases the wave's own Q slice. One barrier per k-tile.
__global__ __launch_bounds__(256) void attn_mfma(
    const __bf16* __restrict__ qkv, const __bf16* __restrict__ vT,
    __bf16* __restrict__ zb)
{
  __shared__ __bf16 Qs[64 * 64];      // Q; later per-wave P slices
  __shared__ __bf16 Ks[2][64 * 64];
  __shared__ __bf16 Vs[3][64 * 64];   // [d][k] (from vT)

  const int tid = threadIdx.x;
  const int lane = tid & 63, wave = tid >> 6;
  const int l16 = lane & 15, quad = lane >> 4;
  const int bx = blockIdx.x;
  const int qt = 31 - (bx >> 5);       // heavy q-tiles dispatched first
  const int bh = bx & 31;
  const int h = bh & 15, b = bh >> 4;
  const int q0 = qt * 64;

  const __bf16* qg = qkv + (size_t)b * 2048 * 3072 + h * 64;
  const __bf16* kg = qg + 1024;
  const __bf16* vg = vT + (size_t)bh * 64 * 2048;

#define STAGE_KV(kt_, kbuf, vbuf)                                               \
  { const int kn = (kt_) * 64;                                                  \
    _Pragma("unroll")                                                           \
    for (int i = 0; i < 2; ++i) {                                               \
      int slot = i * 256 + tid;                                                 \
      int row = slot >> 3, ph2 = slot & 7;                                      \
      int cs = ph2 ^ (row & 7);                                                 \
      gload_lds16(kg + (size_t)(kn + row) * 3072 + cs * 8, &Ks[kbuf][slot * 8]);\
      gload_lds16(vg + (size_t)row * 2048 + kn + cs * 8, &Vs[vbuf][slot * 8]);  \
    } }

  // prologue: Q + K/V tile 0
#pragma unroll
  for (int i = 0; i < 2; ++i) {
    int slot = i * 256 + tid;
    int row = slot >> 3, ph2 = slot & 7;
    int cs = ph2 ^ (row & 7);
    gload_lds16(qg + (size_t)(q0 + row) * 3072 + cs * 8, &Qs[slot * 8]);
  }
  STAGE_KV(0, 0, 0)
  __syncthreads();

  const int sw0 = ((quad) ^ (l16 & 7)) * 8;
  const int sw1 = ((quad + 4) ^ (l16 & 7)) * 8;
  const int mrow = wave * 16 + l16;

  bf16x8 qf0 = *(const bf16x8*)&Qs[mrow * 64 + sw0];
  bf16x8 qf1 = *(const bf16x8*)&Qs[mrow * 64 + sw1];
  __bf16* P = &Qs[wave * 16 * 64];    // this wave's own 16x64 slice

  bf16x8 onesf;
  {
    __bf16 ov = (l16 == 0) ? (__bf16)1.0f : (__bf16)0.0f;
#pragma unroll
    for (int i = 0; i < 8; ++i) onesf[i] = ov;
  }

  const f32x4 zero = {0.f, 0.f, 0.f, 0.f};
  f32x4 O[4], Ol = zero;
#pragma unroll
  for (int j = 0; j < 4; ++j) O[j] = zero;
  f32x4 s_cur[4], s_next[4];

#define S_TILE(sdst, kb)                                                        \
  { _Pragma("unroll")                                                           \
    for (int j = 0; j < 4; ++j) sdst[j] = zero;                                 \
    _Pragma("unroll")                                                           \
    for (int j = 0; j < 4; ++j) {                                               \
      bf16x8 kf0 = *(const bf16x8*)&Ks[kb][(j * 16 + l16) * 64 + sw0];          \
      sdst[j] = __builtin_amdgcn_mfma_f32_16x16x32_bf16(qf0, kf0, sdst[j],0,0,0);\
      bf16x8 kf1 = *(const bf16x8*)&Ks[kb][(j * 16 + l16) * 64 + sw1];          \
      sdst[j] = __builtin_amdgcn_mfma_f32_16x16x32_bf16(qf1, kf1, sdst[j],0,0,0);\
    } }

#define EXP_P(s, DIAG)                                                          \
  { _Pragma("unroll")                                                           \
    for (int j = 0; j < 4; ++j) {                                               \
      _Pragma("unroll")                                                         \
      for (int g = 0; g < 4; ++g) {                                             \
        float p = __builtin_exp2f(s[j][g]);                                     \
        if (DIAG && (j * 16 + l16) > (wave * 16 + quad * 4 + g)) p = 0.f;       \
        s[j][g] = p;                                                            \
      }                                                                         \
    }                                                                           \
    _Pragma("unroll")                                                           \
    for (int j = 0; j < 4; ++j) {                                               \
      const int col = j * 16 + l16;                                             \
      const int ch = col >> 3, cin = col & 7;                                   \
      _Pragma("unroll")                                                         \
      for (int g = 0; g < 4; ++g) {                                             \
        const int row = quad * 4 + g;                                           \
        P[row * 64 + ((ch ^ (row & 7)) * 8) + cin] = (__bf16)s[j][g];           \
      }                                                                         \
    } }

#define PV_TILE(vb)                                                             \
  { bf16x8 pf0 = *(const bf16x8*)&P[l16 * 64 + sw0];                            \
    bf16x8 pf1 = *(const bf16x8*)&P[l16 * 64 + sw1];                            \
    _Pragma("unroll")                                                           \
    for (int j = 0; j < 4; ++j) {                                               \
      bf16x8 vf0 = *(const bf16x8*)&Vs[vb][(j * 16 + l16) * 64 + sw0];          \
      O[j] = __builtin_amdgcn_mfma_f32_16x16x32_bf16(pf0, vf0, O[j], 0, 0, 0);  \
      bf16x8 vf1 = *(const bf16x8*)&Vs[vb][(j * 16 + l16) * 64 + sw1];          \
      O[j] = __builtin_amdgcn_mfma_f32_16x16x32_bf16(pf1, vf1, O[j], 0, 0, 0);  \
    }                                                                           \
    Ol = __builtin_amdgcn_mfma_f32_16x16x32_bf16(pf0, onesf, Ol, 0, 0, 0);      \
    Ol = __builtin_amdgcn_mfma_f32_16x16x32_bf16(pf1, onesf, Ol, 0, 0, 0); }

  // pipeline prologue: stage tile 1, compute S(0)
  if (qt > 0) STAGE_KV(1, 1, 1)
  S_TILE(s_cur, 0)
  if (qt > 0) __syncthreads();   // drains stage(1)

  for (int t = 0; t < qt; ++t) {
    EXP_P(s_cur, false)                    // VALU of tile t ...
    S_TILE(s_next, (t + 1) & 1)            // ... overlaps MFMA of tile t+1
    PV_TILE(t % 3)
    if (t + 2 <= qt) STAGE_KV(t + 2, t & 1, (t + 2) % 3)
    __syncthreads();
#pragma unroll
    for (int j = 0; j < 4; ++j) s_cur[j] = s_next[j];
  }
  // diagonal (masked) tile
  EXP_P(s_cur, true)
  PV_TILE(qt % 3)

  // epilogue: l lives in col 0 of Ol (lanes l16==0); broadcast within quad
  const int rq = q0 + wave * 16 + quad * 4;
#pragma unroll
  for (int g = 0; g < 4; ++g) {
    const float lv = __shfl(Ol[g], quad * 16);
    const float inv = 1.0f / lv;
    const size_t rb = (size_t)(b * 2048 + rq + g) * 1024 + h * 64 + l16;
#pragma unroll
    for (int j = 0; j < 4; ++j)
      zb[rb + j * 16] = (__bf16)(O[j][g] * inv);
  }
}

// ---------------- launch ----------------
extern "C" void kernel_launch(void* const* d_in, const int* in_sizes, int n_in,
                              void* d_out, int out_size, void* d_ws, size_t ws_size,
                              hipStream_t stream) {
  (void)in_sizes; (void)n_in; (void)out_size; (void)ws_size;
  const float* x  = (const float*)d_in[0];
  const float* Wq = (const float*)d_in[1];
  const float* bq = (const float*)d_in[2];
  const float* Wk = (const float*)d_in[3];
  const float* bk = (const float*)d_in[4];
  const float* Wv = (const float*)d_in[5];
  const float* bv = (const float*)d_in[6];
  const float* Wo = (const float*)d_in[7];
  const float* bo = (const float*)d_in[8];

  char* ws = (char*)d_ws;
  __bf16* xb   = (__bf16*)(ws);                        // 8 MB
  __bf16* wqkv = (__bf16*)(ws + (8ull  << 20));        // 6 MB
  __bf16* wob  = (__bf16*)(ws + (14ull << 20));        // 2 MB
  float*  bqkv = (float*) (ws + (16ull << 20));        // 12 KB
  __bf16* qkv  = (__bf16*)(ws + (17ull << 20));        // 24 MB
  __bf16* vT   = (__bf16*)(ws + (41ull << 20));        // 8 MB  [bh][64][2048]
  __bf16* zb   = (__bf16*)(ws + (49ull << 20));        // 8 MB  (total 57 MB)

  cvt_kernel<<<4097, 256, 0, stream>>>(x, Wq, Wk, Wv, Wo, bq, bk, bv,
                                       xb, wqkv, wob, bqkv);
  gemm_k<128, 128, 1><<<dim3(24, 32), 256, 0, stream>>>(
      xb, wqkv, bqkv, nullptr, qkv, vT, Mx, 3072, 1024, 0);
  attn_mfma<<<1024, 256, 0, stream>>>(qkv, vT, zb);
  gemm_k<128, 64, 0><<<dim3(16, 32), 256, 0, stream>>>(
      zb, wob, bo, (float*)d_out, nullptr, nullptr, Mx, 1024, 1024, 1024);
}